// Round 9
// baseline (226.147 us; speedup 1.0000x reference)
//
#include <hip/hip_runtime.h>

#define N_NODES 50000
#define N_EDGES 800000
#define N_GRAPHS 64
#define SCAN_BLOCKS 196              // 196*256 = 50176 >= N_NODES

// CSR build partitioning: zero device atomics
#define NCHUNK 32
#define CHUNK_E (N_EDGES / NCHUNK)   // 25000
#define NRANGE 4
#define RSZ (N_NODES / NRANGE)       // 12500 counters = 50KB LDS

// src-range bucketing (for gather locality)
#define NSRCR 16
#define SRCR_SZ (N_NODES / NSRCR)    // 3125
#define WCHUNK (CHUNK_E / 4)         // 6250 edges per wave

// sA partition: srchist | embed | prep
#define SA_HIST NCHUNK                    // 32
#define SA_EMBED (N_NODES * 16 / 256)     // 3125
#define SA_PREP 32

typedef __bf16 bf16x8 __attribute__((ext_vector_type(8)));
typedef float f32x4 __attribute__((ext_vector_type(4)));

// ---- bf16 helpers (RN-even pack, exact unpack) ----
static __device__ __forceinline__ unsigned short f2bf(float f) {
    union { float f; unsigned u; } v; v.f = f;
    unsigned u = v.u;
    u += 0x7fffu + ((u >> 16) & 1u);          // round-to-nearest-even
    return (unsigned short)(u >> 16);
}
static __device__ __forceinline__ float bflo(unsigned w) {
    union { unsigned u; float f; } v; v.u = w << 16; return v.f;
}
static __device__ __forceinline__ float bfhi(unsigned w) {
    union { unsigned u; float f; } v; v.u = w & 0xffff0000u; return v.f;
}

// ---------------- sA: per-(chunk,wave) src-range hist | embed | weight prep ----------------
__global__ __launch_bounds__(256) void sA_kernel(const int* __restrict__ src,
                                                 int* __restrict__ scnt,
                                                 const int* __restrict__ x_idx,
                                                 const float* __restrict__ table,
                                                 unsigned short* __restrict__ X,
                                                 const float* __restrict__ Wl1,
                                                 const float* __restrict__ Wr1,
                                                 const float* __restrict__ Wl2,
                                                 const float* __restrict__ Wr2,
                                                 unsigned short* __restrict__ blob,
                                                 float* __restrict__ gsum) {
    const int b = blockIdx.x;
    if (b < SA_HIST) {
        // per-wave histogram of src ranges within chunk b
        __shared__ int h[4][NSRCR];
        const int t = threadIdx.x, w = t >> 6, lane = t & 63;
        if (t < 64) h[t >> 4][t & 15] = 0;
        __syncthreads();
        const int* s = src + b * CHUNK_E + w * WCHUNK;
        for (int i = lane; i < WCHUNK; i += 64) {
            unsigned r = (unsigned)s[i] / SRCR_SZ;
            atomicAdd(&h[w][r], 1);
        }
        __syncthreads();
        if (t < 64) scnt[(b * 4 + (t >> 4)) * NSRCR + (t & 15)] = h[t >> 4][t & 15];
    } else if (b < SA_HIST + SA_EMBED) {
        // embedding gather -> bf16 row-major [N][128]
        int i = (b - SA_HIST) * 256 + threadIdx.x;   // node*16 + 8-feat chunk
        int n = i >> 4, cq = i & 15;
        const float4* sp = (const float4*)(table + (size_t)x_idx[n] * 128 + cq * 8);
        float4 a = sp[0], bb = sp[1];
        uint4 o;
        o.x = (unsigned)f2bf(a.x)  | ((unsigned)f2bf(a.y)  << 16);
        o.y = (unsigned)f2bf(a.z)  | ((unsigned)f2bf(a.w)  << 16);
        o.z = (unsigned)f2bf(bb.x) | ((unsigned)f2bf(bb.y) << 16);
        o.w = (unsigned)f2bf(bb.z) | ((unsigned)f2bf(bb.w) << 16);
        ((uint4*)X)[i] = o;
    } else {
        // weight prep (frag-ordered bf16 blob) + gsum zero
        int s = (b - SA_HIST - SA_EMBED) * 256 + threadIdx.x;   // [0, 8192)
        gsum[s] = 0.f;
        int g = s >> 12;
        int sl = s & 4095;
        int fidx = sl >> 6, lane = sl & 63;
        int m = fidx >> 5, kk = (fidx >> 3) & 3, tile = fidx & 7;
        const float* W = g ? (m ? Wr2 : Wl2) : (m ? Wr1 : Wl1);
        int n  = tile * 16 + (lane & 15);
        int k0 = kk * 32 + (lane >> 4) * 8;
        const float4* sp = (const float4*)(W + n * 128 + k0);
        float4 a = sp[0], bb = sp[1];
        uint4 o;
        o.x = (unsigned)f2bf(a.x)  | ((unsigned)f2bf(a.y)  << 16);
        o.y = (unsigned)f2bf(a.z)  | ((unsigned)f2bf(a.w)  << 16);
        o.z = (unsigned)f2bf(bb.x) | ((unsigned)f2bf(bb.y) << 16);
        o.w = (unsigned)f2bf(bb.z) | ((unsigned)f2bf(bb.w) << 16);
        ((uint4*)blob)[s] = o;
    }
}

// ---------------- sB: scatter edges into src-range-ordered e2 arrays ----------------
__global__ __launch_bounds__(256) void sB_kernel(const int* __restrict__ src,
                                                 const int* __restrict__ dst,
                                                 const int* __restrict__ scnt,
                                                 int* __restrict__ e2src,
                                                 int* __restrict__ e2dst) {
    __shared__ int sc[NCHUNK * 4 * NSRCR];     // 2048 ints
    __shared__ int tot[NSRCR];
    __shared__ int base[4][NSRCR];
    __shared__ int cnt[4][NSRCR];
    const int t = threadIdx.x, c = blockIdx.x;
    for (int i = t; i < NCHUNK * 4 * NSRCR; i += 256) sc[i] = scnt[i];
    __syncthreads();
    if (t < NSRCR) {
        int s = 0;
        for (int cw = 0; cw < NCHUNK * 4; ++cw) s += sc[cw * NSRCR + t];
        tot[t] = s;
    }
    __syncthreads();
    if (t < 64) {
        int w = t >> 4, r = t & 15;
        int rs = 0;
        for (int r2 = 0; r2 < r; ++r2) rs += tot[r2];
        int p = 0, lim = c * 4 + w;
        for (int cw = 0; cw < lim; ++cw) p += sc[cw * NSRCR + r];
        base[w][r] = rs + p;
        cnt[w][r] = 0;
    }
    __syncthreads();
    const int w = t >> 6, lane = t & 63;
    const int* sp = src + c * CHUNK_E + w * WCHUNK;
    const int* dp = dst + c * CHUNK_E + w * WCHUNK;
    for (int i = lane; i < WCHUNK; i += 64) {
        int sv = sp[i], dv = dp[i];
        unsigned r = (unsigned)sv / SRCR_SZ;
        int pos = base[w][r] + atomicAdd(&cnt[w][r], 1);
        e2src[pos] = sv;
        e2dst[pos] = dv;
    }
}

// ---------------- histpart: per-(chunk,range) LDS histogram of e2dst ----------------
__global__ __launch_bounds__(256) void histpart_kernel(const int* __restrict__ dst,
                                                       int* __restrict__ part) {
    __shared__ int h[RSZ];
    const int c = blockIdx.x >> 2;
    const int r = blockIdx.x & 3;
    const int rbase = r * RSZ;
    for (int i = threadIdx.x; i < RSZ; i += 256) h[i] = 0;
    __syncthreads();
    const int4* d4 = (const int4*)(dst + c * CHUNK_E);
    for (int i = threadIdx.x; i < CHUNK_E / 4; i += 256) {
        int4 d = d4[i];
        unsigned a;
        a = (unsigned)(d.x - rbase); if (a < RSZ) atomicAdd(&h[a], 1);
        a = (unsigned)(d.y - rbase); if (a < RSZ) atomicAdd(&h[a], 1);
        a = (unsigned)(d.z - rbase); if (a < RSZ) atomicAdd(&h[a], 1);
        a = (unsigned)(d.w - rbase); if (a < RSZ) atomicAdd(&h[a], 1);
    }
    __syncthreads();
    int* p = part + (size_t)c * N_NODES + rbase;
    for (int i = threadIdx.x; i < RSZ; i += 256) p[i] = h[i];
}

// ---------------- cnt + per-block sum (fused) ----------------
__global__ __launch_bounds__(256) void cntsum_kernel(const int* __restrict__ part,
                                                     int* __restrict__ cnt,
                                                     int* __restrict__ bsum) {
    int t = threadIdx.x;
    int n = blockIdx.x * 256 + t;
    int s = 0;
    if (n < N_NODES) {
#pragma unroll
        for (int c = 0; c < NCHUNK; ++c) s += part[(size_t)c * N_NODES + n];
        cnt[n] = s;
    }
#pragma unroll
    for (int off = 32; off > 0; off >>= 1) s += __shfl_down(s, off, 64);
    __shared__ int ws[4];
    if ((t & 63) == 0) ws[t >> 6] = s;
    __syncthreads();
    if (t == 0) bsum[blockIdx.x] = ws[0] + ws[1] + ws[2] + ws[3];
}

// ---------------- rowptr + per-chunk offsets (with inline block-offset scan) ----------------
__global__ __launch_bounds__(256) void rowptroff_kernel(const int* __restrict__ cnt,
                                                        const int* __restrict__ bsum,
                                                        const int* __restrict__ part,
                                                        int* __restrict__ rowptr,
                                                        int* __restrict__ off) {
    __shared__ int sb[256];
    __shared__ int sd[256];
    int t = threadIdx.x;
    sb[t] = (t < SCAN_BLOCKS) ? bsum[t] : 0;
    __syncthreads();
    for (int o = 1; o < 256; o <<= 1) {
        int add = (t >= o) ? sb[t - o] : 0;
        __syncthreads();
        sb[t] += add;
        __syncthreads();
    }
    int boff = (blockIdx.x > 0) ? sb[blockIdx.x - 1] : 0;

    int i = blockIdx.x * 256 + t;
    int v = (i < N_NODES) ? cnt[i] : 0;
    sd[t] = v;
    __syncthreads();
    for (int o = 1; o < 256; o <<= 1) {
        int add = (t >= o) ? sd[t - o] : 0;
        __syncthreads();
        sd[t] += add;
        __syncthreads();
    }
    int excl = sd[t] - v + boff;
    if (i < N_NODES) {
        rowptr[i] = excl;
        if (i == N_NODES - 1) rowptr[N_NODES] = excl + v;
        int run = excl;
#pragma unroll
        for (int c = 0; c < NCHUNK; ++c) {
            off[(size_t)c * N_NODES + i] = run;
            run += part[(size_t)c * N_NODES + i];
        }
    }
}

// ---------------- CSR scatter (consumes src-range-ordered e2 arrays) ----------------
// chunk index == position order => every csr row ends up internally src-range sorted.
__global__ __launch_bounds__(256) void scatter_kernel(const int* __restrict__ src,
                                                      const int* __restrict__ dst,
                                                      const int* __restrict__ off,
                                                      int* __restrict__ csr) {
    __shared__ int h[RSZ];
    const int c = blockIdx.x >> 2;
    const int r = blockIdx.x & 3;
    const int rbase = r * RSZ;
    const int* o = off + (size_t)c * N_NODES + rbase;
    for (int i = threadIdx.x; i < RSZ; i += 256) h[i] = o[i];
    __syncthreads();
    const int4* d4 = (const int4*)(dst + c * CHUNK_E);
    const int4* s4 = (const int4*)(src + c * CHUNK_E);
    for (int i = threadIdx.x; i < CHUNK_E / 4; i += 256) {
        int4 d = d4[i];
        int4 s = s4[i];
        unsigned a;
        a = (unsigned)(d.x - rbase); if (a < RSZ) csr[atomicAdd(&h[a], 1)] = s.x;
        a = (unsigned)(d.y - rbase); if (a < RSZ) csr[atomicAdd(&h[a], 1)] = s.y;
        a = (unsigned)(d.z - rbase); if (a < RSZ) csr[atomicAdd(&h[a], 1)] = s.z;
        a = (unsigned)(d.w - rbase); if (a < RSZ) csr[atomicAdd(&h[a], 1)] = s.w;
    }
}

// ---------------- mean aggregation: 4 nodes/wave, 16 lanes x 16B per 256B row ----------------
// csr rows are src-range-ordered -> concurrent waves walk the 16 src windows in phase.
__global__ __launch_bounds__(256) void agg_kernel(const unsigned short* __restrict__ X,
                                                  const int* __restrict__ rowptr,
                                                  const int* __restrict__ csr,
                                                  unsigned short* __restrict__ AGG) {
    const int t = threadIdx.x;
    const int lane = t & 63;
    const int f = lane & 15;
    const int n = blockIdx.x * 16 + (t >> 6) * 4 + (lane >> 4);
    int beg = rowptr[n], end = rowptr[n + 1];
    const char* Xb = (const char*)X + f * 16;
    float a0 = 0.f, a1 = 0.f, a2 = 0.f, a3 = 0.f,
          a4 = 0.f, a5 = 0.f, a6 = 0.f, a7 = 0.f;
    int i = beg;
    for (; i + 4 <= end; i += 4) {
        int s0 = csr[i], s1 = csr[i + 1], s2 = csr[i + 2], s3 = csr[i + 3];
        uint4 v0 = *(const uint4*)(Xb + (size_t)s0 * 256);
        uint4 v1 = *(const uint4*)(Xb + (size_t)s1 * 256);
        uint4 v2 = *(const uint4*)(Xb + (size_t)s2 * 256);
        uint4 v3 = *(const uint4*)(Xb + (size_t)s3 * 256);
        a0 += (bflo(v0.x) + bflo(v1.x)) + (bflo(v2.x) + bflo(v3.x));
        a1 += (bfhi(v0.x) + bfhi(v1.x)) + (bfhi(v2.x) + bfhi(v3.x));
        a2 += (bflo(v0.y) + bflo(v1.y)) + (bflo(v2.y) + bflo(v3.y));
        a3 += (bfhi(v0.y) + bfhi(v1.y)) + (bfhi(v2.y) + bfhi(v3.y));
        a4 += (bflo(v0.z) + bflo(v1.z)) + (bflo(v2.z) + bflo(v3.z));
        a5 += (bfhi(v0.z) + bfhi(v1.z)) + (bfhi(v2.z) + bfhi(v3.z));
        a6 += (bflo(v0.w) + bflo(v1.w)) + (bflo(v2.w) + bflo(v3.w));
        a7 += (bfhi(v0.w) + bfhi(v1.w)) + (bfhi(v2.w) + bfhi(v3.w));
    }
    for (; i < end; ++i) {
        uint4 v0 = *(const uint4*)(Xb + (size_t)csr[i] * 256);
        a0 += bflo(v0.x); a1 += bfhi(v0.x);
        a2 += bflo(v0.y); a3 += bfhi(v0.y);
        a4 += bflo(v0.z); a5 += bfhi(v0.z);
        a6 += bflo(v0.w); a7 += bfhi(v0.w);
    }
    float inv = 1.f / (float)max(end - beg, 1);
    uint4 o;
    o.x = (unsigned)f2bf(a0 * inv) | ((unsigned)f2bf(a1 * inv) << 16);
    o.y = (unsigned)f2bf(a2 * inv) | ((unsigned)f2bf(a3 * inv) << 16);
    o.z = (unsigned)f2bf(a4 * inv) | ((unsigned)f2bf(a5 * inv) << 16);
    o.w = (unsigned)f2bf(a6 * inv) | ((unsigned)f2bf(a7 * inv) << 16);
    *(uint4*)((char*)AGG + (size_t)n * 256 + f * 16) = o;
}

// ---------------- fused SAGE linear via MFMA (layer 1: 2 tiles/block) ----------------
__global__ __launch_bounds__(256) void gemm_kernel(const unsigned short* __restrict__ A0,
                                                   const unsigned short* __restrict__ A1,
                                                   const unsigned short* __restrict__ wblob,
                                                   const float* __restrict__ bias,
                                                   unsigned short* __restrict__ Y) {
    __shared__ char lds[65536];
    const int t = threadIdx.x, lane = t & 63, w = t >> 6;

    {
        const char* src = (const char*)wblob + w * 16384 + lane * 16;
        char* dst = lds + w * 16384;
#pragma unroll
        for (int i = 0; i < 16; ++i) {
            __builtin_amdgcn_global_load_lds(
                (const __attribute__((address_space(1))) unsigned*)(src + i * 1024),
                (__attribute__((address_space(3))) unsigned*)(dst + i * 1024), 16, 0, 0);
        }
    }
    __syncthreads();

    const int kl = (lane >> 4) * 8;
    const int c     = lane & 15;
    const int rbase = (lane >> 4) * 4;

#pragma unroll 1
    for (int tt = 0; tt < 2; ++tt) {
        const int tile0 = blockIdx.x * 2 + tt;
        if (tile0 * 128 >= N_NODES) break;
        const int row0 = tile0 * 128 + w * 32;

        f32x4 acc[2][8];
#pragma unroll
        for (int rt = 0; rt < 2; ++rt)
#pragma unroll
            for (int tl = 0; tl < 8; ++tl) acc[rt][tl] = (f32x4){0.f, 0.f, 0.f, 0.f};

        int rA = min(row0 + (lane & 15),      N_NODES - 1);
        int rB = min(row0 + 16 + (lane & 15), N_NODES - 1);

#pragma unroll
        for (int km = 0; km < 8; ++km) {
            const unsigned short* A = (km < 4) ? A0 : A1;
            int k0 = (km & 3) * 32 + kl;
            bf16x8 a0 = *(const bf16x8*)(A + (size_t)rA * 128 + k0);
            bf16x8 a1 = *(const bf16x8*)(A + (size_t)rB * 128 + k0);
            const char* bbase = lds + km * 8192 + lane * 16;
#pragma unroll
            for (int tile = 0; tile < 8; ++tile) {
                bf16x8 b = *(const bf16x8*)(bbase + tile * 1024);
                acc[0][tile] = __builtin_amdgcn_mfma_f32_16x16x32_bf16(a0, b, acc[0][tile], 0, 0, 0);
                acc[1][tile] = __builtin_amdgcn_mfma_f32_16x16x32_bf16(a1, b, acc[1][tile], 0, 0, 0);
            }
        }

#pragma unroll
        for (int rt = 0; rt < 2; ++rt) {
#pragma unroll
            for (int tile = 0; tile < 8; ++tile) {
                int col = tile * 16 + c;
                float bv = bias[col];
#pragma unroll
                for (int j = 0; j < 4; ++j) {
                    int r = row0 + rt * 16 + rbase + j;
                    if (r < N_NODES)
                        Y[(size_t)r * 128 + col] = f2bf(fmaxf(acc[rt][tile][j] + bv, 0.f));
                }
            }
        }
    }
}

// ---------------- layer-2 GEMM with fused mean-pool (no y2 write) ----------------
__global__ __launch_bounds__(256) void gemm_pool_kernel(const unsigned short* __restrict__ A0,
                                                        const unsigned short* __restrict__ A1,
                                                        const unsigned short* __restrict__ wblob,
                                                        const float* __restrict__ bias,
                                                        const int* __restrict__ batch,
                                                        float* __restrict__ gsum) {
    __shared__ char lds[65536];
    const int t = threadIdx.x, lane = t & 63, w = t >> 6;
    const int brow0 = blockIdx.x * 128;
    const int row0  = brow0 + w * 32;

    {
        const char* src = (const char*)wblob + w * 16384 + lane * 16;
        char* dst = lds + w * 16384;
#pragma unroll
        for (int i = 0; i < 16; ++i) {
            __builtin_amdgcn_global_load_lds(
                (const __attribute__((address_space(1))) unsigned*)(src + i * 1024),
                (__attribute__((address_space(3))) unsigned*)(dst + i * 1024), 16, 0, 0);
        }
    }
    __syncthreads();

    f32x4 acc[2][8];
#pragma unroll
    for (int rt = 0; rt < 2; ++rt)
#pragma unroll
        for (int tl = 0; tl < 8; ++tl) acc[rt][tl] = (f32x4){0.f, 0.f, 0.f, 0.f};

    int rA = min(row0 + (lane & 15),      N_NODES - 1);
    int rB = min(row0 + 16 + (lane & 15), N_NODES - 1);
    const int kl = (lane >> 4) * 8;

#pragma unroll
    for (int km = 0; km < 8; ++km) {
        const unsigned short* A = (km < 4) ? A0 : A1;
        int k0 = (km & 3) * 32 + kl;
        bf16x8 a0 = *(const bf16x8*)(A + (size_t)rA * 128 + k0);
        bf16x8 a1 = *(const bf16x8*)(A + (size_t)rB * 128 + k0);
        const char* bbase = lds + km * 8192 + lane * 16;
#pragma unroll
        for (int tile = 0; tile < 8; ++tile) {
            bf16x8 b = *(const bf16x8*)(bbase + tile * 1024);
            acc[0][tile] = __builtin_amdgcn_mfma_f32_16x16x32_bf16(a0, b, acc[0][tile], 0, 0, 0);
            acc[1][tile] = __builtin_amdgcn_mfma_f32_16x16x32_bf16(a1, b, acc[1][tile], 0, 0, 0);
        }
    }

    // epilogue: relu(acc+bias) -> reuse weight LDS as 128x128 f32 tile
    __syncthreads();                       // all waves done reading weights
    float* ftile = (float*)lds;
    const int c     = lane & 15;
    const int rbase = (lane >> 4) * 4;
#pragma unroll
    for (int rt = 0; rt < 2; ++rt) {
#pragma unroll
        for (int tile = 0; tile < 8; ++tile) {
            int col = tile * 16 + c;
            float bv = bias[col];
#pragma unroll
            for (int j = 0; j < 4; ++j) {
                int lr = w * 32 + rt * 16 + rbase + j;
                ftile[lr * 128 + col] = fmaxf(acc[rt][tile][j] + bv, 0.f);
            }
        }
    }
    __syncthreads();

    // per-graph column partial sums (batch sorted): thread = (col, row-half)
    const int col  = t & 127;
    const int half = t >> 7;
    float s = 0.f;
    int curg = -1;
    for (int rr = 0; rr < 64; ++rr) {
        int r = brow0 + half * 64 + rr;
        if (r >= N_NODES) break;
        int g = batch[r];
        if (g != curg) {
            if (curg >= 0) atomicAdd(&gsum[curg * 128 + col], s);
            curg = g; s = 0.f;
        }
        s += ftile[(half * 64 + rr) * 128 + col];
    }
    if (curg >= 0) atomicAdd(&gsum[curg * 128 + col], s);
}

// ---------------- classifier ----------------
__global__ void final_kernel(const float* __restrict__ gsum, const int* __restrict__ batch,
                             const float* __restrict__ linW, const float* __restrict__ linb,
                             float* __restrict__ out) {
    int t = blockIdx.x * 256 + threadIdx.x;
    if (t >= N_GRAPHS * 10) return;
    int g = t / 10, j = t % 10;
    int bnd[2];
    for (int c = 0; c < 2; ++c) {
        int target = g + c;
        int lo = 0, hi = N_NODES;
        while (lo < hi) { int mid = (lo + hi) >> 1; if (batch[mid] < target) lo = mid + 1; else hi = mid; }
        bnd[c] = lo;
    }
    float invc = 1.f / (float)max(bnd[1] - bnd[0], 1);
    float s = 0.f;
    for (int k = 0; k < 128; ++k) s += gsum[g * 128 + k] * linW[j * 128 + k];
    out[t] = linb[j] + s * invc;
}

extern "C" void kernel_launch(void* const* d_in, const int* in_sizes, int n_in,
                              void* d_out, int out_size, void* d_ws, size_t ws_size,
                              hipStream_t stream) {
    const int*   x_idx = (const int*)d_in[0];
    const int*   eidx  = (const int*)d_in[1];   // [2][N_EDGES]
    const int*   batch = (const int*)d_in[2];
    const float* table = (const float*)d_in[3];
    const float* Wl1   = (const float*)d_in[4];
    const float* bl1   = (const float*)d_in[5];
    const float* Wr1   = (const float*)d_in[6];
    const float* Wl2   = (const float*)d_in[7];
    const float* bl2   = (const float*)d_in[8];
    const float* Wr2   = (const float*)d_in[9];
    const float* linW  = (const float*)d_in[10];
    const float* linb  = (const float*)d_in[11];
    float*       out   = (float*)d_out;

    const int* src = eidx;
    const int* dst = eidx + N_EDGES;

    // workspace layout (~62 MB); feature buffers row-major [N][128] bf16
    unsigned short* X    = (unsigned short*)d_ws;                 // x0
    unsigned short* AGG  = X   + (size_t)N_NODES * 128;           // agg
    unsigned short* Y1   = AGG + (size_t)N_NODES * 128;           // y1
    unsigned short* blob = Y1  + (size_t)N_NODES * 128;           // 2 x 64KB frag-ordered
    float* gsum = (float*)(blob + 65536);
    int* cnt    = (int*)(gsum + N_GRAPHS * 128);
    int* rowptr = cnt + N_NODES;                                  // N_NODES+1
    int* csr    = rowptr + (N_NODES + 1);                         // N_EDGES
    int* bsum   = csr + N_EDGES;                                  // SCAN_BLOCKS
    int* part   = bsum + SCAN_BLOCKS;                             // NCHUNK x N_NODES
    int* off    = part + (size_t)NCHUNK * N_NODES;                // NCHUNK x N_NODES
    int* e2src  = off + (size_t)NCHUNK * N_NODES;                 // N_EDGES
    int* e2dst  = e2src + N_EDGES;                                // N_EDGES
    int* scnt   = e2dst + N_EDGES;                                // NCHUNK*4*NSRCR

    // src-range bucket + embed + weight prep
    sA_kernel<<<SA_HIST + SA_EMBED + SA_PREP, 256, 0, stream>>>(
        src, scnt, x_idx, table, X, Wl1, Wr1, Wl2, Wr2, blob, gsum);
    sB_kernel<<<NCHUNK, 256, 0, stream>>>(src, dst, scnt, e2src, e2dst);

    // CSR build on src-ordered edges (no device atomics)
    histpart_kernel <<<NCHUNK * NRANGE, 256, 0, stream>>>(e2dst, part);
    cntsum_kernel   <<<SCAN_BLOCKS, 256, 0, stream>>>(part, cnt, bsum);
    rowptroff_kernel<<<SCAN_BLOCKS, 256, 0, stream>>>(cnt, bsum, part, rowptr, off);
    scatter_kernel  <<<NCHUNK * NRANGE, 256, 0, stream>>>(e2src, e2dst, off, csr);

    // layer 1
    agg_kernel <<<dim3(N_NODES / 16), 256, 0, stream>>>(X, rowptr, csr, AGG);
    gemm_kernel<<<dim3((N_NODES + 255) / 256), 256, 0, stream>>>(AGG, X, blob, bl1, Y1);
    // layer 2 (+ fused mean pool)
    agg_kernel      <<<dim3(N_NODES / 16), 256, 0, stream>>>(Y1, rowptr, csr, AGG);
    gemm_pool_kernel<<<dim3((N_NODES + 127) / 128), 256, 0, stream>>>(AGG, Y1, blob + 32768, bl2, batch, gsum);

    final_kernel<<<3, 256, 0, stream>>>(gsum, batch, linW, linb, out);
}

// Round 10
// 204.960 us; speedup vs baseline: 1.1034x; 1.1034x over previous
//
#include <hip/hip_runtime.h>

#define N_NODES 50000
#define N_EDGES 800000
#define N_GRAPHS 64
#define SCAN_BLOCKS 196              // 196*256 = 50176 >= N_NODES

// CSR build partitioning: zero device atomics
#define NCHUNK 32
#define CHUNK_E (N_EDGES / NCHUNK)   // 25000
#define NRANGE 4
#define RSZ (N_NODES / NRANGE)       // 12500 counters = 50KB LDS

// fat k1 partition
#define K1_HIST (NCHUNK * NRANGE)    // 128 blocks
#define K1_EMBED (N_NODES * 16 / 256) // 3125 blocks
#define K1_PREP 32                   // 8192 threads: weight prep + gsum zero

typedef __bf16 bf16x8 __attribute__((ext_vector_type(8)));
typedef float f32x4 __attribute__((ext_vector_type(4)));
typedef unsigned uint32x4v __attribute__((ext_vector_type(4)));

// ---- bf16 helpers (RN-even pack, exact unpack) ----
static __device__ __forceinline__ unsigned short f2bf(float f) {
    union { float f; unsigned u; } v; v.f = f;
    unsigned u = v.u;
    u += 0x7fffu + ((u >> 16) & 1u);          // round-to-nearest-even
    return (unsigned short)(u >> 16);
}
static __device__ __forceinline__ float bflo(unsigned w) {
    union { unsigned u; float f; } v; v.u = w << 16; return v.f;
}
static __device__ __forceinline__ float bfhi(unsigned w) {
    union { unsigned u; float f; } v; v.u = w & 0xffff0000u; return v.f;
}

#define ACC8(A, v) do { \
    A[0] += bflo((v).x); A[1] += bfhi((v).x); \
    A[2] += bflo((v).y); A[3] += bfhi((v).y); \
    A[4] += bflo((v).z); A[5] += bfhi((v).z); \
    A[6] += bflo((v).w); A[7] += bfhi((v).w); } while (0)

// ---------------- k1: histpart | embed | weight-prep + gsum zero ----------------
__global__ __launch_bounds__(256) void k1_kernel(const int* __restrict__ dst,
                                                 int* __restrict__ part,
                                                 const int* __restrict__ x_idx,
                                                 const float* __restrict__ table,
                                                 unsigned short* __restrict__ X,
                                                 const float* __restrict__ Wl1,
                                                 const float* __restrict__ Wr1,
                                                 const float* __restrict__ Wl2,
                                                 const float* __restrict__ Wr2,
                                                 unsigned short* __restrict__ blob,
                                                 float* __restrict__ gsum) {
    const int b = blockIdx.x;
    if (b < K1_HIST) {
        __shared__ int h[RSZ];
        const int c = b >> 2;            // chunk
        const int r = b & 3;             // node range
        const int rbase = r * RSZ;
        for (int i = threadIdx.x; i < RSZ; i += 256) h[i] = 0;
        __syncthreads();
        const int4* d4 = (const int4*)(dst + c * CHUNK_E);
        for (int i = threadIdx.x; i < CHUNK_E / 4; i += 256) {
            int4 d = d4[i];
            unsigned a;
            a = (unsigned)(d.x - rbase); if (a < RSZ) atomicAdd(&h[a], 1);
            a = (unsigned)(d.y - rbase); if (a < RSZ) atomicAdd(&h[a], 1);
            a = (unsigned)(d.z - rbase); if (a < RSZ) atomicAdd(&h[a], 1);
            a = (unsigned)(d.w - rbase); if (a < RSZ) atomicAdd(&h[a], 1);
        }
        __syncthreads();
        int* p = part + (size_t)c * N_NODES + rbase;
        for (int i = threadIdx.x; i < RSZ; i += 256) p[i] = h[i];
    } else if (b < K1_HIST + K1_EMBED) {
        // embedding gather -> bf16 row-major [N][128]
        int i = (b - K1_HIST) * 256 + threadIdx.x;   // node*16 + 8-feat chunk
        int n = i >> 4, cq = i & 15;
        const float4* src = (const float4*)(table + (size_t)x_idx[n] * 128 + cq * 8);
        float4 a = src[0], bb = src[1];
        uint4 o;
        o.x = (unsigned)f2bf(a.x)  | ((unsigned)f2bf(a.y)  << 16);
        o.y = (unsigned)f2bf(a.z)  | ((unsigned)f2bf(a.w)  << 16);
        o.z = (unsigned)f2bf(bb.x) | ((unsigned)f2bf(bb.y) << 16);
        o.w = (unsigned)f2bf(bb.z) | ((unsigned)f2bf(bb.w) << 16);
        ((uint4*)X)[i] = o;
    } else {
        // weight prep (frag-ordered bf16 blob) + gsum zero
        int s = (b - K1_HIST - K1_EMBED) * 256 + threadIdx.x;   // [0, 8192)
        gsum[s] = 0.f;
        int g = s >> 12;
        int sl = s & 4095;
        int fidx = sl >> 6, lane = sl & 63;
        int m = fidx >> 5, kk = (fidx >> 3) & 3, tile = fidx & 7;
        const float* W = g ? (m ? Wr2 : Wl2) : (m ? Wr1 : Wl1);
        int n  = tile * 16 + (lane & 15);
        int k0 = kk * 32 + (lane >> 4) * 8;
        const float4* src = (const float4*)(W + n * 128 + k0);
        float4 a = src[0], bb = src[1];
        uint4 o;
        o.x = (unsigned)f2bf(a.x)  | ((unsigned)f2bf(a.y)  << 16);
        o.y = (unsigned)f2bf(a.z)  | ((unsigned)f2bf(a.w)  << 16);
        o.z = (unsigned)f2bf(bb.x) | ((unsigned)f2bf(bb.y) << 16);
        o.w = (unsigned)f2bf(bb.z) | ((unsigned)f2bf(bb.w) << 16);
        ((uint4*)blob)[s] = o;
    }
}

// ---------------- cnt + per-block sum (fused) ----------------
__global__ __launch_bounds__(256) void cntsum_kernel(const int* __restrict__ part,
                                                     int* __restrict__ cnt,
                                                     int* __restrict__ bsum) {
    int t = threadIdx.x;
    int n = blockIdx.x * 256 + t;
    int s = 0;
    if (n < N_NODES) {
#pragma unroll
        for (int c = 0; c < NCHUNK; ++c) s += part[(size_t)c * N_NODES + n];
        cnt[n] = s;
    }
#pragma unroll
    for (int off = 32; off > 0; off >>= 1) s += __shfl_down(s, off, 64);
    __shared__ int ws[4];
    if ((t & 63) == 0) ws[t >> 6] = s;
    __syncthreads();
    if (t == 0) bsum[blockIdx.x] = ws[0] + ws[1] + ws[2] + ws[3];
}

// ---------------- rowptr + per-chunk offsets (with inline block-offset scan) ----------------
__global__ __launch_bounds__(256) void rowptroff_kernel(const int* __restrict__ cnt,
                                                        const int* __restrict__ bsum,
                                                        const int* __restrict__ part,
                                                        int* __restrict__ rowptr,
                                                        int* __restrict__ off) {
    __shared__ int sb[256];
    __shared__ int sd[256];
    int t = threadIdx.x;
    sb[t] = (t < SCAN_BLOCKS) ? bsum[t] : 0;
    __syncthreads();
    for (int o = 1; o < 256; o <<= 1) {
        int add = (t >= o) ? sb[t - o] : 0;
        __syncthreads();
        sb[t] += add;
        __syncthreads();
    }
    int boff = (blockIdx.x > 0) ? sb[blockIdx.x - 1] : 0;

    int i = blockIdx.x * 256 + t;
    int v = (i < N_NODES) ? cnt[i] : 0;
    sd[t] = v;
    __syncthreads();
    for (int o = 1; o < 256; o <<= 1) {
        int add = (t >= o) ? sd[t - o] : 0;
        __syncthreads();
        sd[t] += add;
        __syncthreads();
    }
    int excl = sd[t] - v + boff;
    if (i < N_NODES) {
        rowptr[i] = excl;
        if (i == N_NODES - 1) rowptr[N_NODES] = excl + v;
        int run = excl;
#pragma unroll
        for (int c = 0; c < NCHUNK; ++c) {
            off[(size_t)c * N_NODES + i] = run;
            run += part[(size_t)c * N_NODES + i];
        }
    }
}

// ---------------- scatter, LDS position counters, no device atomics ----------------
__global__ __launch_bounds__(256) void scatter_kernel(const int* __restrict__ src,
                                                      const int* __restrict__ dst,
                                                      const int* __restrict__ off,
                                                      int* __restrict__ csr) {
    __shared__ int h[RSZ];
    const int c = blockIdx.x >> 2;
    const int r = blockIdx.x & 3;
    const int rbase = r * RSZ;
    const int* o = off + (size_t)c * N_NODES + rbase;
    for (int i = threadIdx.x; i < RSZ; i += 256) h[i] = o[i];
    __syncthreads();
    const int4* d4 = (const int4*)(dst + c * CHUNK_E);
    const int4* s4 = (const int4*)(src + c * CHUNK_E);
    for (int i = threadIdx.x; i < CHUNK_E / 4; i += 256) {
        int4 d = d4[i];
        int4 s = s4[i];
        unsigned a;
        a = (unsigned)(d.x - rbase); if (a < RSZ) csr[atomicAdd(&h[a], 1)] = s.x;
        a = (unsigned)(d.y - rbase); if (a < RSZ) csr[atomicAdd(&h[a], 1)] = s.y;
        a = (unsigned)(d.z - rbase); if (a < RSZ) csr[atomicAdd(&h[a], 1)] = s.z;
        a = (unsigned)(d.w - rbase); if (a < RSZ) csr[atomicAdd(&h[a], 1)] = s.w;
    }
}

// ---------------- fused SAGE layer: gather-mean + MFMA (+ optional pool) ----------------
// block = 128 rows, 4 waves x 32 rows. lane (rr=lane&15, jc=lane>>4):
// owns rows rA=row0+rr, rB=rA+16 and feature chunks {jc*8 + 32j}, j=0..3 (8 bf16 each).
// 4 lanes with equal rr collectively read each 256B neighbor row. Agg accumulates in
// registers, converts straight to MFMA A-fragments -- no AGG buffer, no A-tile LDS.
// Weights staged via global_load_lds, drained by the single barrier (overlaps gather).
template<int POOL>
__global__ __launch_bounds__(256) void sage_kernel(const unsigned short* __restrict__ Xf,
                                                   const int* __restrict__ rowptr,
                                                   const int* __restrict__ csr,
                                                   const unsigned short* __restrict__ wblob,
                                                   const float* __restrict__ bias,
                                                   unsigned short* __restrict__ Y,
                                                   const int* __restrict__ batch,
                                                   float* __restrict__ gsum) {
    __shared__ char lds[65536];
    const int t = threadIdx.x, lane = t & 63, w = t >> 6;
    const int brow0 = blockIdx.x * 128;
    const int row0  = brow0 + w * 32;
    const int rr = lane & 15;
    const int jc = lane >> 4;

    // issue weight staging first; completes under the gather
    {
        const char* srcp = (const char*)wblob + w * 16384 + lane * 16;
        char* dstp = lds + w * 16384;
#pragma unroll
        for (int i = 0; i < 16; ++i) {
            __builtin_amdgcn_global_load_lds(
                (const __attribute__((address_space(1))) unsigned*)(srcp + i * 1024),
                (__attribute__((address_space(3))) unsigned*)(dstp + i * 1024), 16, 0, 0);
        }
    }

    const int rA = min(row0 + rr,      N_NODES - 1);
    const int rB = min(row0 + 16 + rr, N_NODES - 1);

    // self-row fragments (lin_r operand), prefetched
    bf16x8 xA[4], xB[4];
#pragma unroll
    for (int j = 0; j < 4; ++j) {
        xA[j] = *(const bf16x8*)((const char*)Xf + (size_t)rA * 256 + j * 64 + jc * 16);
        xB[j] = *(const bf16x8*)((const char*)Xf + (size_t)rB * 256 + j * 64 + jc * 16);
    }

    // gather-mean accumulate (fp32)
    float aA[4][8], aB[4][8];
#pragma unroll
    for (int j = 0; j < 4; ++j)
#pragma unroll
        for (int e = 0; e < 8; ++e) { aA[j][e] = 0.f; aB[j][e] = 0.f; }

    const int begA = rowptr[rA], endA = rowptr[rA + 1];
    const int begB = rowptr[rB], endB = rowptr[rB + 1];
    const char* Xb = (const char*)Xf + jc * 16;

    {
        int i = begA;
        for (; i + 2 <= endA; i += 2) {
            int s0 = csr[i], s1 = csr[i + 1];
            const char* p0 = Xb + (size_t)s0 * 256;
            const char* p1 = Xb + (size_t)s1 * 256;
            uint4 u0 = *(const uint4*)(p0),       u1 = *(const uint4*)(p0 + 64);
            uint4 u2 = *(const uint4*)(p0 + 128), u3 = *(const uint4*)(p0 + 192);
            uint4 v0 = *(const uint4*)(p1),       v1 = *(const uint4*)(p1 + 64);
            uint4 v2 = *(const uint4*)(p1 + 128), v3 = *(const uint4*)(p1 + 192);
            ACC8(aA[0], u0); ACC8(aA[1], u1); ACC8(aA[2], u2); ACC8(aA[3], u3);
            ACC8(aA[0], v0); ACC8(aA[1], v1); ACC8(aA[2], v2); ACC8(aA[3], v3);
        }
        if (i < endA) {
            const char* p0 = Xb + (size_t)csr[i] * 256;
            uint4 u0 = *(const uint4*)(p0),       u1 = *(const uint4*)(p0 + 64);
            uint4 u2 = *(const uint4*)(p0 + 128), u3 = *(const uint4*)(p0 + 192);
            ACC8(aA[0], u0); ACC8(aA[1], u1); ACC8(aA[2], u2); ACC8(aA[3], u3);
        }
    }
    {
        int i = begB;
        for (; i + 2 <= endB; i += 2) {
            int s0 = csr[i], s1 = csr[i + 1];
            const char* p0 = Xb + (size_t)s0 * 256;
            const char* p1 = Xb + (size_t)s1 * 256;
            uint4 u0 = *(const uint4*)(p0),       u1 = *(const uint4*)(p0 + 64);
            uint4 u2 = *(const uint4*)(p0 + 128), u3 = *(const uint4*)(p0 + 192);
            uint4 v0 = *(const uint4*)(p1),       v1 = *(const uint4*)(p1 + 64);
            uint4 v2 = *(const uint4*)(p1 + 128), v3 = *(const uint4*)(p1 + 192);
            ACC8(aB[0], u0); ACC8(aB[1], u1); ACC8(aB[2], u2); ACC8(aB[3], u3);
            ACC8(aB[0], v0); ACC8(aB[1], v1); ACC8(aB[2], v2); ACC8(aB[3], v3);
        }
        if (i < endB) {
            const char* p0 = Xb + (size_t)csr[i] * 256;
            uint4 u0 = *(const uint4*)(p0),       u1 = *(const uint4*)(p0 + 64);
            uint4 u2 = *(const uint4*)(p0 + 128), u3 = *(const uint4*)(p0 + 192);
            ACC8(aB[0], u0); ACC8(aB[1], u1); ACC8(aB[2], u2); ACC8(aB[3], u3);
        }
    }

    // mean + convert to bf16 A-fragments (same rounding point as the old AGG buffer)
    const float invA = 1.f / (float)max(endA - begA, 1);
    const float invB = 1.f / (float)max(endB - begB, 1);
    bf16x8 fA[4], fB[4];
#pragma unroll
    for (int j = 0; j < 4; ++j) {
        uint32x4v ua, ub;
#pragma unroll
        for (int p = 0; p < 4; ++p) {
            ua[p] = (unsigned)f2bf(aA[j][2 * p] * invA) |
                    ((unsigned)f2bf(aA[j][2 * p + 1] * invA) << 16);
            ub[p] = (unsigned)f2bf(aB[j][2 * p] * invB) |
                    ((unsigned)f2bf(aB[j][2 * p + 1] * invB) << 16);
        }
        fA[j] = __builtin_bit_cast(bf16x8, ua);
        fB[j] = __builtin_bit_cast(bf16x8, ub);
    }

    __syncthreads();   // drains weight staging (vmcnt) + aligns waves

    // MFMA: K=256 (agg||x), all 128 cols
    f32x4 acc[2][8];
#pragma unroll
    for (int rt = 0; rt < 2; ++rt)
#pragma unroll
        for (int tl = 0; tl < 8; ++tl) acc[rt][tl] = (f32x4){0.f, 0.f, 0.f, 0.f};

#pragma unroll
    for (int km = 0; km < 8; ++km) {
        bf16x8 a0 = (km < 4) ? fA[km] : xA[km - 4];
        bf16x8 a1 = (km < 4) ? fB[km] : xB[km - 4];
        const char* bbase = lds + km * 8192 + lane * 16;
#pragma unroll
        for (int tile = 0; tile < 8; ++tile) {
            bf16x8 b = *(const bf16x8*)(bbase + tile * 1024);
            acc[0][tile] = __builtin_amdgcn_mfma_f32_16x16x32_bf16(a0, b, acc[0][tile], 0, 0, 0);
            acc[1][tile] = __builtin_amdgcn_mfma_f32_16x16x32_bf16(a1, b, acc[1][tile], 0, 0, 0);
        }
    }

    // epilogue. C/D: col=lane&15, row=(lane>>4)*4+j
    const int c     = lane & 15;
    const int rbase = (lane >> 4) * 4;
    if (POOL == 0) {
#pragma unroll
        for (int rt = 0; rt < 2; ++rt) {
#pragma unroll
            for (int tile = 0; tile < 8; ++tile) {
                int col = tile * 16 + c;
                float bv = bias[col];
#pragma unroll
                for (int j = 0; j < 4; ++j) {
                    int r = row0 + rt * 16 + rbase + j;
                    if (r < N_NODES)
                        Y[(size_t)r * 128 + col] = f2bf(fmaxf(acc[rt][tile][j] + bv, 0.f));
                }
            }
        }
    } else {
        // relu(acc+bias) -> reuse weight LDS as 128x128 f32 tile, then per-graph pool
        __syncthreads();                   // all waves done reading weights
        float* ftile = (float*)lds;
#pragma unroll
        for (int rt = 0; rt < 2; ++rt) {
#pragma unroll
            for (int tile = 0; tile < 8; ++tile) {
                int col = tile * 16 + c;
                float bv = bias[col];
#pragma unroll
                for (int j = 0; j < 4; ++j) {
                    int lr = w * 32 + rt * 16 + rbase + j;
                    ftile[lr * 128 + col] = fmaxf(acc[rt][tile][j] + bv, 0.f);
                }
            }
        }
        __syncthreads();
        // per-graph column partial sums (batch sorted): thread = (col, row-half)
        const int col  = t & 127;
        const int half = t >> 7;
        float s = 0.f;
        int curg = -1;
        for (int rr2 = 0; rr2 < 64; ++rr2) {
            int r = brow0 + half * 64 + rr2;
            if (r >= N_NODES) break;
            int g = batch[r];
            if (g != curg) {
                if (curg >= 0) atomicAdd(&gsum[curg * 128 + col], s);
                curg = g; s = 0.f;
            }
            s += ftile[(half * 64 + rr2) * 128 + col];
        }
        if (curg >= 0) atomicAdd(&gsum[curg * 128 + col], s);
    }
}

// ---------------- classifier ----------------
__global__ void final_kernel(const float* __restrict__ gsum, const int* __restrict__ batch,
                             const float* __restrict__ linW, const float* __restrict__ linb,
                             float* __restrict__ out) {
    int t = blockIdx.x * 256 + threadIdx.x;
    if (t >= N_GRAPHS * 10) return;
    int g = t / 10, j = t % 10;
    int bnd[2];
    for (int c = 0; c < 2; ++c) {
        int target = g + c;
        int lo = 0, hi = N_NODES;
        while (lo < hi) { int mid = (lo + hi) >> 1; if (batch[mid] < target) lo = mid + 1; else hi = mid; }
        bnd[c] = lo;
    }
    float invc = 1.f / (float)max(bnd[1] - bnd[0], 1);
    float s = 0.f;
    for (int k = 0; k < 128; ++k) s += gsum[g * 128 + k] * linW[j * 128 + k];
    out[t] = linb[j] + s * invc;
}

extern "C" void kernel_launch(void* const* d_in, const int* in_sizes, int n_in,
                              void* d_out, int out_size, void* d_ws, size_t ws_size,
                              hipStream_t stream) {
    const int*   x_idx = (const int*)d_in[0];
    const int*   eidx  = (const int*)d_in[1];   // [2][N_EDGES]
    const int*   batch = (const int*)d_in[2];
    const float* table = (const float*)d_in[3];
    const float* Wl1   = (const float*)d_in[4];
    const float* bl1   = (const float*)d_in[5];
    const float* Wr1   = (const float*)d_in[6];
    const float* Wl2   = (const float*)d_in[7];
    const float* bl2   = (const float*)d_in[8];
    const float* Wr2   = (const float*)d_in[9];
    const float* linW  = (const float*)d_in[10];
    const float* linb  = (const float*)d_in[11];
    float*       out   = (float*)d_out;

    const int* src = eidx;
    const int* dst = eidx + N_EDGES;

    // workspace layout (~42 MB); feature buffers row-major [N][128] bf16
    unsigned short* X    = (unsigned short*)d_ws;                 // x0
    unsigned short* Y1   = X  + (size_t)N_NODES * 128;            // y1
    unsigned short* blob = Y1 + (size_t)N_NODES * 128;            // 2 x 64KB frag-ordered
    float* gsum = (float*)(blob + 65536);
    int* cnt    = (int*)(gsum + N_GRAPHS * 128);
    int* rowptr = cnt + N_NODES;                                  // N_NODES+1
    int* csr    = rowptr + (N_NODES + 1);                         // N_EDGES
    int* bsum   = csr + N_EDGES;                                  // SCAN_BLOCKS
    int* part   = bsum + SCAN_BLOCKS;                             // NCHUNK x N_NODES
    int* off    = part + (size_t)NCHUNK * N_NODES;                // NCHUNK x N_NODES

    // k1: histogram | embed | weight prep + gsum zero (one launch)
    k1_kernel<<<K1_HIST + K1_EMBED + K1_PREP, 256, 0, stream>>>(
        dst, part, x_idx, table, X, Wl1, Wr1, Wl2, Wr2, blob, gsum);
    cntsum_kernel   <<<SCAN_BLOCKS, 256, 0, stream>>>(part, cnt, bsum);
    rowptroff_kernel<<<SCAN_BLOCKS, 256, 0, stream>>>(cnt, bsum, part, rowptr, off);
    scatter_kernel  <<<NCHUNK * NRANGE, 256, 0, stream>>>(src, dst, off, csr);

    // layer 1: fused gather-mean + GEMM
    sage_kernel<0><<<dim3((N_NODES + 127) / 128), 256, 0, stream>>>(
        X, rowptr, csr, blob, bl1, Y1, nullptr, nullptr);
    // layer 2: fused gather-mean + GEMM + mean-pool
    sage_kernel<1><<<dim3((N_NODES + 127) / 128), 256, 0, stream>>>(
        Y1, rowptr, csr, blob + 32768, bl2, nullptr, batch, gsum);

    final_kernel<<<3, 256, 0, stream>>>(gsum, batch, linW, linb, out);
}

// Round 11
// 161.641 us; speedup vs baseline: 1.3991x; 1.2680x over previous
//
#include <hip/hip_runtime.h>

#define N_NODES 50000
#define N_EDGES 800000
#define N_GRAPHS 64
#define SCAN_BLOCKS 196              // 196*256 = 50176 >= N_NODES

// CSR build partitioning: zero device atomics
#define NCHUNK 32
#define CHUNK_E (N_EDGES / NCHUNK)   // 25000
#define NRANGE 4
#define RSZ (N_NODES / NRANGE)       // 12500 counters = 50KB LDS

// fat k1 partition
#define K1_HIST (NCHUNK * NRANGE)    // 128 blocks
#define K1_EMBED (N_NODES * 16 / 256) // 3125 blocks
#define K1_PREP 32                   // 8192 threads: weight prep + gsum zero

typedef __bf16 bf16x8 __attribute__((ext_vector_type(8)));
typedef float f32x4 __attribute__((ext_vector_type(4)));

// ---- bf16 helpers (RN-even pack, exact unpack) ----
static __device__ __forceinline__ unsigned short f2bf(float f) {
    union { float f; unsigned u; } v; v.f = f;
    unsigned u = v.u;
    u += 0x7fffu + ((u >> 16) & 1u);          // round-to-nearest-even
    return (unsigned short)(u >> 16);
}
static __device__ __forceinline__ float bflo(unsigned w) {
    union { unsigned u; float f; } v; v.u = w << 16; return v.f;
}
static __device__ __forceinline__ float bfhi(unsigned w) {
    union { unsigned u; float f; } v; v.u = w & 0xffff0000u; return v.f;
}

#define ACC8(A, v) do { \
    A[0] += bflo((v).x); A[1] += bfhi((v).x); \
    A[2] += bflo((v).y); A[3] += bfhi((v).y); \
    A[4] += bflo((v).z); A[5] += bfhi((v).z); \
    A[6] += bflo((v).w); A[7] += bfhi((v).w); } while (0)

// ---------------- k1: histpart | embed | weight-prep + gsum zero ----------------
__global__ __launch_bounds__(256) void k1_kernel(const int* __restrict__ dst,
                                                 int* __restrict__ part,
                                                 const int* __restrict__ x_idx,
                                                 const float* __restrict__ table,
                                                 unsigned short* __restrict__ X,
                                                 const float* __restrict__ Wl1,
                                                 const float* __restrict__ Wr1,
                                                 const float* __restrict__ Wl2,
                                                 const float* __restrict__ Wr2,
                                                 unsigned short* __restrict__ blob,
                                                 float* __restrict__ gsum) {
    const int b = blockIdx.x;
    if (b < K1_HIST) {
        __shared__ int h[RSZ];
        const int c = b >> 2;            // chunk
        const int r = b & 3;             // node range
        const int rbase = r * RSZ;
        for (int i = threadIdx.x; i < RSZ; i += 256) h[i] = 0;
        __syncthreads();
        const int4* d4 = (const int4*)(dst + c * CHUNK_E);
        for (int i = threadIdx.x; i < CHUNK_E / 4; i += 256) {
            int4 d = d4[i];
            unsigned a;
            a = (unsigned)(d.x - rbase); if (a < RSZ) atomicAdd(&h[a], 1);
            a = (unsigned)(d.y - rbase); if (a < RSZ) atomicAdd(&h[a], 1);
            a = (unsigned)(d.z - rbase); if (a < RSZ) atomicAdd(&h[a], 1);
            a = (unsigned)(d.w - rbase); if (a < RSZ) atomicAdd(&h[a], 1);
        }
        __syncthreads();
        int* p = part + (size_t)c * N_NODES + rbase;
        for (int i = threadIdx.x; i < RSZ; i += 256) p[i] = h[i];
    } else if (b < K1_HIST + K1_EMBED) {
        // embedding gather -> bf16 row-major [N][128]
        int i = (b - K1_HIST) * 256 + threadIdx.x;   // node*16 + 8-feat chunk
        int n = i >> 4, cq = i & 15;
        const float4* src = (const float4*)(table + (size_t)x_idx[n] * 128 + cq * 8);
        float4 a = src[0], bb = src[1];
        uint4 o;
        o.x = (unsigned)f2bf(a.x)  | ((unsigned)f2bf(a.y)  << 16);
        o.y = (unsigned)f2bf(a.z)  | ((unsigned)f2bf(a.w)  << 16);
        o.z = (unsigned)f2bf(bb.x) | ((unsigned)f2bf(bb.y) << 16);
        o.w = (unsigned)f2bf(bb.z) | ((unsigned)f2bf(bb.w) << 16);
        ((uint4*)X)[i] = o;
    } else {
        // weight prep (frag-ordered bf16 blob) + gsum zero
        int s = (b - K1_HIST - K1_EMBED) * 256 + threadIdx.x;   // [0, 8192)
        gsum[s] = 0.f;
        int g = s >> 12;
        int sl = s & 4095;
        int fidx = sl >> 6, lane = sl & 63;
        int m = fidx >> 5, kk = (fidx >> 3) & 3, tile = fidx & 7;
        const float* W = g ? (m ? Wr2 : Wl2) : (m ? Wr1 : Wl1);
        int n  = tile * 16 + (lane & 15);
        int k0 = kk * 32 + (lane >> 4) * 8;
        const float4* src = (const float4*)(W + n * 128 + k0);
        float4 a = src[0], bb = src[1];
        uint4 o;
        o.x = (unsigned)f2bf(a.x)  | ((unsigned)f2bf(a.y)  << 16);
        o.y = (unsigned)f2bf(a.z)  | ((unsigned)f2bf(a.w)  << 16);
        o.z = (unsigned)f2bf(bb.x) | ((unsigned)f2bf(bb.y) << 16);
        o.w = (unsigned)f2bf(bb.z) | ((unsigned)f2bf(bb.w) << 16);
        ((uint4*)blob)[s] = o;
    }
}

// ---------------- cnt + per-block sum (fused) ----------------
__global__ __launch_bounds__(256) void cntsum_kernel(const int* __restrict__ part,
                                                     int* __restrict__ cnt,
                                                     int* __restrict__ bsum) {
    int t = threadIdx.x;
    int n = blockIdx.x * 256 + t;
    int s = 0;
    if (n < N_NODES) {
#pragma unroll
        for (int c = 0; c < NCHUNK; ++c) s += part[(size_t)c * N_NODES + n];
        cnt[n] = s;
    }
#pragma unroll
    for (int off = 32; off > 0; off >>= 1) s += __shfl_down(s, off, 64);
    __shared__ int ws[4];
    if ((t & 63) == 0) ws[t >> 6] = s;
    __syncthreads();
    if (t == 0) bsum[blockIdx.x] = ws[0] + ws[1] + ws[2] + ws[3];
}

// ---------------- rowptr + per-chunk offsets (with inline block-offset scan) ----------------
__global__ __launch_bounds__(256) void rowptroff_kernel(const int* __restrict__ cnt,
                                                        const int* __restrict__ bsum,
                                                        const int* __restrict__ part,
                                                        int* __restrict__ rowptr,
                                                        int* __restrict__ off) {
    __shared__ int sb[256];
    __shared__ int sd[256];
    int t = threadIdx.x;
    sb[t] = (t < SCAN_BLOCKS) ? bsum[t] : 0;
    __syncthreads();
    for (int o = 1; o < 256; o <<= 1) {
        int add = (t >= o) ? sb[t - o] : 0;
        __syncthreads();
        sb[t] += add;
        __syncthreads();
    }
    int boff = (blockIdx.x > 0) ? sb[blockIdx.x - 1] : 0;

    int i = blockIdx.x * 256 + t;
    int v = (i < N_NODES) ? cnt[i] : 0;
    sd[t] = v;
    __syncthreads();
    for (int o = 1; o < 256; o <<= 1) {
        int add = (t >= o) ? sd[t - o] : 0;
        __syncthreads();
        sd[t] += add;
        __syncthreads();
    }
    int excl = sd[t] - v + boff;
    if (i < N_NODES) {
        rowptr[i] = excl;
        if (i == N_NODES - 1) rowptr[N_NODES] = excl + v;
        int run = excl;
#pragma unroll
        for (int c = 0; c < NCHUNK; ++c) {
            off[(size_t)c * N_NODES + i] = run;
            run += part[(size_t)c * N_NODES + i];
        }
    }
}

// ---------------- scatter, LDS position counters, no device atomics ----------------
__global__ __launch_bounds__(256) void scatter_kernel(const int* __restrict__ src,
                                                      const int* __restrict__ dst,
                                                      const int* __restrict__ off,
                                                      int* __restrict__ csr) {
    __shared__ int h[RSZ];
    const int c = blockIdx.x >> 2;
    const int r = blockIdx.x & 3;
    const int rbase = r * RSZ;
    const int* o = off + (size_t)c * N_NODES + rbase;
    for (int i = threadIdx.x; i < RSZ; i += 256) h[i] = o[i];
    __syncthreads();
    const int4* d4 = (const int4*)(dst + c * CHUNK_E);
    const int4* s4 = (const int4*)(src + c * CHUNK_E);
    for (int i = threadIdx.x; i < CHUNK_E / 4; i += 256) {
        int4 d = d4[i];
        int4 s = s4[i];
        unsigned a;
        a = (unsigned)(d.x - rbase); if (a < RSZ) csr[atomicAdd(&h[a], 1)] = s.x;
        a = (unsigned)(d.y - rbase); if (a < RSZ) csr[atomicAdd(&h[a], 1)] = s.y;
        a = (unsigned)(d.z - rbase); if (a < RSZ) csr[atomicAdd(&h[a], 1)] = s.z;
        a = (unsigned)(d.w - rbase); if (a < RSZ) csr[atomicAdd(&h[a], 1)] = s.w;
    }
}

// ---------------- mean aggregation: ONE node per wave, 4 edge-slots x 16 lanes ----------------
// lane (e=lane>>4, f=lane&15): slot e walks edges beg+e, beg+4+e, ...; 16 lanes with
// equal e read one 256B neighbor row. No inter-node divergence (trip count = own
// degree); final sum across slots = 2 x shfl_xor. One load instr = 4 edges.
__global__ __launch_bounds__(256) void agg_kernel(const unsigned short* __restrict__ X,
                                                  const int* __restrict__ rowptr,
                                                  const int* __restrict__ csr,
                                                  unsigned short* __restrict__ AGG) {
    const int t = threadIdx.x;
    const int lane = t & 63;
    const int e = lane >> 4;                  // edge slot
    const int f = lane & 15;                  // 16B feature chunk
    const int n = blockIdx.x * 4 + (t >> 6);  // one node per wave
    const int beg = rowptr[n], end = rowptr[n + 1];
    const char* Xb = (const char*)X + f * 16;
    float a[8];
#pragma unroll
    for (int k = 0; k < 8; ++k) a[k] = 0.f;

    int i = beg;
    for (; i + 8 <= end; i += 8) {            // 8 edges: 2 row-loads in flight
        int c0 = csr[i + e];
        int c1 = csr[i + 4 + e];
        uint4 v0 = *(const uint4*)(Xb + (size_t)c0 * 256);
        uint4 v1 = *(const uint4*)(Xb + (size_t)c1 * 256);
        ACC8(a, v0);
        ACC8(a, v1);
    }
    if (i + 4 <= end) {
        int c0 = csr[i + e];
        uint4 v0 = *(const uint4*)(Xb + (size_t)c0 * 256);
        ACC8(a, v0);
        i += 4;
    }
    if (i + e < end) {                        // remainder 0..3 edges
        int c0 = csr[i + e];
        uint4 v0 = *(const uint4*)(Xb + (size_t)c0 * 256);
        ACC8(a, v0);
    }

    // reduce across the 4 edge slots (lanes f, 16+f, 32+f, 48+f)
#pragma unroll
    for (int k = 0; k < 8; ++k) {
        a[k] += __shfl_xor(a[k], 16, 64);
        a[k] += __shfl_xor(a[k], 32, 64);
    }

    if (e == 0) {
        float inv = 1.f / (float)max(end - beg, 1);
        uint4 o;
        o.x = (unsigned)f2bf(a[0] * inv) | ((unsigned)f2bf(a[1] * inv) << 16);
        o.y = (unsigned)f2bf(a[2] * inv) | ((unsigned)f2bf(a[3] * inv) << 16);
        o.z = (unsigned)f2bf(a[4] * inv) | ((unsigned)f2bf(a[5] * inv) << 16);
        o.w = (unsigned)f2bf(a[6] * inv) | ((unsigned)f2bf(a[7] * inv) << 16);
        *(uint4*)((char*)AGG + (size_t)n * 256 + f * 16) = o;
    }
}

// ---------------- fused SAGE linear via MFMA (layer 1: 2 tiles/block) ----------------
__global__ __launch_bounds__(256) void gemm_kernel(const unsigned short* __restrict__ A0,
                                                   const unsigned short* __restrict__ A1,
                                                   const unsigned short* __restrict__ wblob,
                                                   const float* __restrict__ bias,
                                                   unsigned short* __restrict__ Y) {
    __shared__ char lds[65536];
    const int t = threadIdx.x, lane = t & 63, w = t >> 6;

    {
        const char* src = (const char*)wblob + w * 16384 + lane * 16;
        char* dst = lds + w * 16384;
#pragma unroll
        for (int i = 0; i < 16; ++i) {
            __builtin_amdgcn_global_load_lds(
                (const __attribute__((address_space(1))) unsigned*)(src + i * 1024),
                (__attribute__((address_space(3))) unsigned*)(dst + i * 1024), 16, 0, 0);
        }
    }
    __syncthreads();

    const int kl = (lane >> 4) * 8;
    const int c     = lane & 15;
    const int rbase = (lane >> 4) * 4;

#pragma unroll 1
    for (int tt = 0; tt < 2; ++tt) {
        const int tile0 = blockIdx.x * 2 + tt;
        if (tile0 * 128 >= N_NODES) break;
        const int row0 = tile0 * 128 + w * 32;

        f32x4 acc[2][8];
#pragma unroll
        for (int rt = 0; rt < 2; ++rt)
#pragma unroll
            for (int tl = 0; tl < 8; ++tl) acc[rt][tl] = (f32x4){0.f, 0.f, 0.f, 0.f};

        int rA = min(row0 + (lane & 15),      N_NODES - 1);
        int rB = min(row0 + 16 + (lane & 15), N_NODES - 1);

#pragma unroll
        for (int km = 0; km < 8; ++km) {
            const unsigned short* A = (km < 4) ? A0 : A1;
            int k0 = (km & 3) * 32 + kl;
            bf16x8 a0 = *(const bf16x8*)(A + (size_t)rA * 128 + k0);
            bf16x8 a1 = *(const bf16x8*)(A + (size_t)rB * 128 + k0);
            const char* bbase = lds + km * 8192 + lane * 16;
#pragma unroll
            for (int tile = 0; tile < 8; ++tile) {
                bf16x8 b = *(const bf16x8*)(bbase + tile * 1024);
                acc[0][tile] = __builtin_amdgcn_mfma_f32_16x16x32_bf16(a0, b, acc[0][tile], 0, 0, 0);
                acc[1][tile] = __builtin_amdgcn_mfma_f32_16x16x32_bf16(a1, b, acc[1][tile], 0, 0, 0);
            }
        }

#pragma unroll
        for (int rt = 0; rt < 2; ++rt) {
#pragma unroll
            for (int tile = 0; tile < 8; ++tile) {
                int col = tile * 16 + c;
                float bv = bias[col];
#pragma unroll
                for (int j = 0; j < 4; ++j) {
                    int r = row0 + rt * 16 + rbase + j;
                    if (r < N_NODES)
                        Y[(size_t)r * 128 + col] = f2bf(fmaxf(acc[rt][tile][j] + bv, 0.f));
                }
            }
        }
    }
}

// ---------------- layer-2 GEMM with fused mean-pool (no y2 write) ----------------
__global__ __launch_bounds__(256) void gemm_pool_kernel(const unsigned short* __restrict__ A0,
                                                        const unsigned short* __restrict__ A1,
                                                        const unsigned short* __restrict__ wblob,
                                                        const float* __restrict__ bias,
                                                        const int* __restrict__ batch,
                                                        float* __restrict__ gsum) {
    __shared__ char lds[65536];
    const int t = threadIdx.x, lane = t & 63, w = t >> 6;
    const int brow0 = blockIdx.x * 128;
    const int row0  = brow0 + w * 32;

    {
        const char* src = (const char*)wblob + w * 16384 + lane * 16;
        char* dst = lds + w * 16384;
#pragma unroll
        for (int i = 0; i < 16; ++i) {
            __builtin_amdgcn_global_load_lds(
                (const __attribute__((address_space(1))) unsigned*)(src + i * 1024),
                (__attribute__((address_space(3))) unsigned*)(dst + i * 1024), 16, 0, 0);
        }
    }
    __syncthreads();

    f32x4 acc[2][8];
#pragma unroll
    for (int rt = 0; rt < 2; ++rt)
#pragma unroll
        for (int tl = 0; tl < 8; ++tl) acc[rt][tl] = (f32x4){0.f, 0.f, 0.f, 0.f};

    int rA = min(row0 + (lane & 15),      N_NODES - 1);
    int rB = min(row0 + 16 + (lane & 15), N_NODES - 1);
    const int kl = (lane >> 4) * 8;

#pragma unroll
    for (int km = 0; km < 8; ++km) {
        const unsigned short* A = (km < 4) ? A0 : A1;
        int k0 = (km & 3) * 32 + kl;
        bf16x8 a0 = *(const bf16x8*)(A + (size_t)rA * 128 + k0);
        bf16x8 a1 = *(const bf16x8*)(A + (size_t)rB * 128 + k0);
        const char* bbase = lds + km * 8192 + lane * 16;
#pragma unroll
        for (int tile = 0; tile < 8; ++tile) {
            bf16x8 b = *(const bf16x8*)(bbase + tile * 1024);
            acc[0][tile] = __builtin_amdgcn_mfma_f32_16x16x32_bf16(a0, b, acc[0][tile], 0, 0, 0);
            acc[1][tile] = __builtin_amdgcn_mfma_f32_16x16x32_bf16(a1, b, acc[1][tile], 0, 0, 0);
        }
    }

    // epilogue: relu(acc+bias) -> reuse weight LDS as 128x128 f32 tile
    __syncthreads();                       // all waves done reading weights
    float* ftile = (float*)lds;
    const int c     = lane & 15;
    const int rbase = (lane >> 4) * 4;
#pragma unroll
    for (int rt = 0; rt < 2; ++rt) {
#pragma unroll
        for (int tile = 0; tile < 8; ++tile) {
            int col = tile * 16 + c;
            float bv = bias[col];
#pragma unroll
            for (int j = 0; j < 4; ++j) {
                int lr = w * 32 + rt * 16 + rbase + j;
                ftile[lr * 128 + col] = fmaxf(acc[rt][tile][j] + bv, 0.f);
            }
        }
    }
    __syncthreads();

    // per-graph column partial sums (batch sorted): thread = (col, row-half)
    const int col  = t & 127;
    const int half = t >> 7;
    float s = 0.f;
    int curg = -1;
    for (int rr = 0; rr < 64; ++rr) {
        int r = brow0 + half * 64 + rr;
        if (r >= N_NODES) break;
        int g = batch[r];
        if (g != curg) {
            if (curg >= 0) atomicAdd(&gsum[curg * 128 + col], s);
            curg = g; s = 0.f;
        }
        s += ftile[(half * 64 + rr) * 128 + col];
    }
    if (curg >= 0) atomicAdd(&gsum[curg * 128 + col], s);
}

// ---------------- classifier ----------------
__global__ void final_kernel(const float* __restrict__ gsum, const int* __restrict__ batch,
                             const float* __restrict__ linW, const float* __restrict__ linb,
                             float* __restrict__ out) {
    int t = blockIdx.x * 256 + threadIdx.x;
    if (t >= N_GRAPHS * 10) return;
    int g = t / 10, j = t % 10;
    int bnd[2];
    for (int c = 0; c < 2; ++c) {
        int target = g + c;
        int lo = 0, hi = N_NODES;
        while (lo < hi) { int mid = (lo + hi) >> 1; if (batch[mid] < target) lo = mid + 1; else hi = mid; }
        bnd[c] = lo;
    }
    float invc = 1.f / (float)max(bnd[1] - bnd[0], 1);
    float s = 0.f;
    for (int k = 0; k < 128; ++k) s += gsum[g * 128 + k] * linW[j * 128 + k];
    out[t] = linb[j] + s * invc;
}

extern "C" void kernel_launch(void* const* d_in, const int* in_sizes, int n_in,
                              void* d_out, int out_size, void* d_ws, size_t ws_size,
                              hipStream_t stream) {
    const int*   x_idx = (const int*)d_in[0];
    const int*   eidx  = (const int*)d_in[1];   // [2][N_EDGES]
    const int*   batch = (const int*)d_in[2];
    const float* table = (const float*)d_in[3];
    const float* Wl1   = (const float*)d_in[4];
    const float* bl1   = (const float*)d_in[5];
    const float* Wr1   = (const float*)d_in[6];
    const float* Wl2   = (const float*)d_in[7];
    const float* bl2   = (const float*)d_in[8];
    const float* Wr2   = (const float*)d_in[9];
    const float* linW  = (const float*)d_in[10];
    const float* linb  = (const float*)d_in[11];
    float*       out   = (float*)d_out;

    const int* src = eidx;
    const int* dst = eidx + N_EDGES;

    // workspace layout (~55 MB); feature buffers row-major [N][128] bf16
    unsigned short* X    = (unsigned short*)d_ws;                 // x0
    unsigned short* AGG  = X   + (size_t)N_NODES * 128;           // agg
    unsigned short* Y1   = AGG + (size_t)N_NODES * 128;           // y1
    unsigned short* blob = Y1  + (size_t)N_NODES * 128;           // 2 x 64KB frag-ordered
    float* gsum = (float*)(blob + 65536);
    int* cnt    = (int*)(gsum + N_GRAPHS * 128);
    int* rowptr = cnt + N_NODES;                                  // N_NODES+1
    int* csr    = rowptr + (N_NODES + 1);                         // N_EDGES
    int* bsum   = csr + N_EDGES;                                  // SCAN_BLOCKS
    int* part   = bsum + SCAN_BLOCKS;                             // NCHUNK x N_NODES
    int* off    = part + (size_t)NCHUNK * N_NODES;                // NCHUNK x N_NODES

    // k1: histogram | embed | weight prep + gsum zero (one launch)
    k1_kernel<<<K1_HIST + K1_EMBED + K1_PREP, 256, 0, stream>>>(
        dst, part, x_idx, table, X, Wl1, Wr1, Wl2, Wr2, blob, gsum);
    cntsum_kernel   <<<SCAN_BLOCKS, 256, 0, stream>>>(part, cnt, bsum);
    rowptroff_kernel<<<SCAN_BLOCKS, 256, 0, stream>>>(cnt, bsum, part, rowptr, off);
    scatter_kernel  <<<NCHUNK * NRANGE, 256, 0, stream>>>(src, dst, off, csr);

    // layer 1
    agg_kernel <<<dim3(N_NODES / 4), 256, 0, stream>>>(X, rowptr, csr, AGG);
    gemm_kernel<<<dim3((N_NODES + 255) / 256), 256, 0, stream>>>(AGG, X, blob, bl1, Y1);
    // layer 2 (+ fused mean pool)
    agg_kernel      <<<dim3(N_NODES / 4), 256, 0, stream>>>(Y1, rowptr, csr, AGG);
    gemm_pool_kernel<<<dim3((N_NODES + 127) / 128), 256, 0, stream>>>(AGG, Y1, blob + 32768, bl2, batch, gsum);

    final_kernel<<<3, 256, 0, stream>>>(gsum, batch, linW, linb, out);
}

// Round 12
// 156.511 us; speedup vs baseline: 1.4449x; 1.0328x over previous
//
#include <hip/hip_runtime.h>

#define N_NODES 50000
#define N_EDGES 800000
#define N_GRAPHS 64
#define VOCAB 1000
#define SCAN_BLOCKS 196              // 196*256 = 50176 >= N_NODES

// CSR build partitioning: zero device atomics
#define NCHUNK 32
#define CHUNK_E (N_EDGES / NCHUNK)   // 25000
#define NRANGE 4
#define RSZ (N_NODES / NRANGE)       // 12500 counters = 50KB LDS

// fat k1 partition
#define K1_HIST (NCHUNK * NRANGE)     // 128 blocks
#define K1_EMBED (N_NODES * 16 / 256) // 3125 blocks
#define K1_TBL 63                     // 1000*16/256 = 62.5 -> 63 blocks (guarded)
#define K1_PREP 32                    // 8192 threads: weight prep + gsum zero

typedef __bf16 bf16x8 __attribute__((ext_vector_type(8)));
typedef float f32x4 __attribute__((ext_vector_type(4)));

// ---- bf16 helpers (RN-even pack, exact unpack) ----
static __device__ __forceinline__ unsigned short f2bf(float f) {
    union { float f; unsigned u; } v; v.f = f;
    unsigned u = v.u;
    u += 0x7fffu + ((u >> 16) & 1u);          // round-to-nearest-even
    return (unsigned short)(u >> 16);
}
static __device__ __forceinline__ float bflo(unsigned w) {
    union { unsigned u; float f; } v; v.u = w << 16; return v.f;
}
static __device__ __forceinline__ float bfhi(unsigned w) {
    union { unsigned u; float f; } v; v.u = w & 0xffff0000u; return v.f;
}

#define ACC8(A, v) do { \
    A[0] += bflo((v).x); A[1] += bfhi((v).x); \
    A[2] += bflo((v).y); A[3] += bfhi((v).y); \
    A[4] += bflo((v).z); A[5] += bfhi((v).z); \
    A[6] += bflo((v).w); A[7] += bfhi((v).w); } while (0)

static __device__ __forceinline__ uint4 cvt2x4(float4 a, float4 b) {
    uint4 o;
    o.x = (unsigned)f2bf(a.x) | ((unsigned)f2bf(a.y) << 16);
    o.y = (unsigned)f2bf(a.z) | ((unsigned)f2bf(a.w) << 16);
    o.z = (unsigned)f2bf(b.x) | ((unsigned)f2bf(b.y) << 16);
    o.w = (unsigned)f2bf(b.z) | ((unsigned)f2bf(b.w) << 16);
    return o;
}

// ---------------- k1: histpart | embed | table-cvt | weight-prep + gsum zero ----------------
__global__ __launch_bounds__(256) void k1_kernel(const int* __restrict__ dst,
                                                 int* __restrict__ part,
                                                 const int* __restrict__ x_idx,
                                                 const float* __restrict__ table,
                                                 unsigned short* __restrict__ X,
                                                 unsigned short* __restrict__ TBL,
                                                 const float* __restrict__ Wl1,
                                                 const float* __restrict__ Wr1,
                                                 const float* __restrict__ Wl2,
                                                 const float* __restrict__ Wr2,
                                                 unsigned short* __restrict__ blob,
                                                 float* __restrict__ gsum) {
    const int b = blockIdx.x;
    if (b < K1_HIST) {
        __shared__ int h[RSZ];
        const int c = b >> 2;            // chunk
        const int r = b & 3;             // node range
        const int rbase = r * RSZ;
        for (int i = threadIdx.x; i < RSZ; i += 256) h[i] = 0;
        __syncthreads();
        const int4* d4 = (const int4*)(dst + c * CHUNK_E);
        for (int i = threadIdx.x; i < CHUNK_E / 4; i += 256) {
            int4 d = d4[i];
            unsigned a;
            a = (unsigned)(d.x - rbase); if (a < RSZ) atomicAdd(&h[a], 1);
            a = (unsigned)(d.y - rbase); if (a < RSZ) atomicAdd(&h[a], 1);
            a = (unsigned)(d.z - rbase); if (a < RSZ) atomicAdd(&h[a], 1);
            a = (unsigned)(d.w - rbase); if (a < RSZ) atomicAdd(&h[a], 1);
        }
        __syncthreads();
        int* p = part + (size_t)c * N_NODES + rbase;
        for (int i = threadIdx.x; i < RSZ; i += 256) p[i] = h[i];
    } else if (b < K1_HIST + K1_EMBED) {
        // embedding gather -> bf16 row-major [N][128] (lin_r operand of layer 1)
        int i = (b - K1_HIST) * 256 + threadIdx.x;   // node*16 + 8-feat chunk
        int n = i >> 4, cq = i & 15;
        const float4* src = (const float4*)(table + (size_t)x_idx[n] * 128 + cq * 8);
        ((uint4*)X)[i] = cvt2x4(src[0], src[1]);
    } else if (b < K1_HIST + K1_EMBED + K1_TBL) {
        // bf16 copy of the embedding table (256KB, L2-resident gather target)
        int i = (b - K1_HIST - K1_EMBED) * 256 + threadIdx.x;   // uint4 slot
        if (i < VOCAB * 16) {
            const float4* src = (const float4*)(table + (size_t)(i >> 4) * 128 + (i & 15) * 8);
            ((uint4*)TBL)[i] = cvt2x4(src[0], src[1]);
        }
    } else {
        // weight prep (frag-ordered bf16 blob) + gsum zero
        int s = (b - K1_HIST - K1_EMBED - K1_TBL) * 256 + threadIdx.x;   // [0, 8192)
        gsum[s] = 0.f;
        int g = s >> 12;
        int sl = s & 4095;
        int fidx = sl >> 6, lane = sl & 63;
        int m = fidx >> 5, kk = (fidx >> 3) & 3, tile = fidx & 7;
        const float* W = g ? (m ? Wr2 : Wl2) : (m ? Wr1 : Wl1);
        int n  = tile * 16 + (lane & 15);
        int k0 = kk * 32 + (lane >> 4) * 8;
        const float4* src = (const float4*)(W + n * 128 + k0);
        ((uint4*)blob)[s] = cvt2x4(src[0], src[1]);
    }
}

// ---------------- cnt + per-block sum (fused) ----------------
__global__ __launch_bounds__(256) void cntsum_kernel(const int* __restrict__ part,
                                                     int* __restrict__ cnt,
                                                     int* __restrict__ bsum) {
    int t = threadIdx.x;
    int n = blockIdx.x * 256 + t;
    int s = 0;
    if (n < N_NODES) {
#pragma unroll
        for (int c = 0; c < NCHUNK; ++c) s += part[(size_t)c * N_NODES + n];
        cnt[n] = s;
    }
#pragma unroll
    for (int off = 32; off > 0; off >>= 1) s += __shfl_down(s, off, 64);
    __shared__ int ws[4];
    if ((t & 63) == 0) ws[t >> 6] = s;
    __syncthreads();
    if (t == 0) bsum[blockIdx.x] = ws[0] + ws[1] + ws[2] + ws[3];
}

// ---------------- rowptr + per-chunk offsets (with inline block-offset scan) ----------------
__global__ __launch_bounds__(256) void rowptroff_kernel(const int* __restrict__ cnt,
                                                        const int* __restrict__ bsum,
                                                        const int* __restrict__ part,
                                                        int* __restrict__ rowptr,
                                                        int* __restrict__ off) {
    __shared__ int sb[256];
    __shared__ int sd[256];
    int t = threadIdx.x;
    sb[t] = (t < SCAN_BLOCKS) ? bsum[t] : 0;
    __syncthreads();
    for (int o = 1; o < 256; o <<= 1) {
        int add = (t >= o) ? sb[t - o] : 0;
        __syncthreads();
        sb[t] += add;
        __syncthreads();
    }
    int boff = (blockIdx.x > 0) ? sb[blockIdx.x - 1] : 0;

    int i = blockIdx.x * 256 + t;
    int v = (i < N_NODES) ? cnt[i] : 0;
    sd[t] = v;
    __syncthreads();
    for (int o = 1; o < 256; o <<= 1) {
        int add = (t >= o) ? sd[t - o] : 0;
        __syncthreads();
        sd[t] += add;
        __syncthreads();
    }
    int excl = sd[t] - v + boff;
    if (i < N_NODES) {
        rowptr[i] = excl;
        if (i == N_NODES - 1) rowptr[N_NODES] = excl + v;
        int run = excl;
#pragma unroll
        for (int c = 0; c < NCHUNK; ++c) {
            off[(size_t)c * N_NODES + i] = run;
            run += part[(size_t)c * N_NODES + i];
        }
    }
}

// ---------------- scatter, LDS position counters, no device atomics ----------------
__global__ __launch_bounds__(256) void scatter_kernel(const int* __restrict__ src,
                                                      const int* __restrict__ dst,
                                                      const int* __restrict__ off,
                                                      int* __restrict__ csr) {
    __shared__ int h[RSZ];
    const int c = blockIdx.x >> 2;
    const int r = blockIdx.x & 3;
    const int rbase = r * RSZ;
    const int* o = off + (size_t)c * N_NODES + rbase;
    for (int i = threadIdx.x; i < RSZ; i += 256) h[i] = o[i];
    __syncthreads();
    const int4* d4 = (const int4*)(dst + c * CHUNK_E);
    const int4* s4 = (const int4*)(src + c * CHUNK_E);
    for (int i = threadIdx.x; i < CHUNK_E / 4; i += 256) {
        int4 d = d4[i];
        int4 s = s4[i];
        unsigned a;
        a = (unsigned)(d.x - rbase); if (a < RSZ) csr[atomicAdd(&h[a], 1)] = s.x;
        a = (unsigned)(d.y - rbase); if (a < RSZ) csr[atomicAdd(&h[a], 1)] = s.y;
        a = (unsigned)(d.z - rbase); if (a < RSZ) csr[atomicAdd(&h[a], 1)] = s.z;
        a = (unsigned)(d.w - rbase); if (a < RSZ) csr[atomicAdd(&h[a], 1)] = s.w;
    }
}

// ---------------- layer-1 aggregation: gather via L2-resident bf16 table ----------------
// X[csr[i]] == TBL[x_idx[csr[i]]]; TBL is 256KB -> every row read is an L2 hit.
// 4 nodes/wave, 16 lanes x 16B per 256B row; 8-deep unroll.
__global__ __launch_bounds__(256) void agg1_kernel(const unsigned short* __restrict__ TBL,
                                                   const int* __restrict__ x_idx,
                                                   const int* __restrict__ rowptr,
                                                   const int* __restrict__ csr,
                                                   unsigned short* __restrict__ AGG) {
    const int t = threadIdx.x;
    const int lane = t & 63;
    const int f = lane & 15;
    const int n = blockIdx.x * 16 + (t >> 6) * 4 + (lane >> 4);
    int beg = rowptr[n], end = rowptr[n + 1];
    const char* Tb = (const char*)TBL + f * 16;
    float a[8];
#pragma unroll
    for (int k = 0; k < 8; ++k) a[k] = 0.f;
    int i = beg;
    for (; i + 8 <= end; i += 8) {
        int r0 = x_idx[csr[i + 0]], r1 = x_idx[csr[i + 1]];
        int r2 = x_idx[csr[i + 2]], r3 = x_idx[csr[i + 3]];
        int r4 = x_idx[csr[i + 4]], r5 = x_idx[csr[i + 5]];
        int r6 = x_idx[csr[i + 6]], r7 = x_idx[csr[i + 7]];
        uint4 v0 = *(const uint4*)(Tb + (size_t)r0 * 256);
        uint4 v1 = *(const uint4*)(Tb + (size_t)r1 * 256);
        uint4 v2 = *(const uint4*)(Tb + (size_t)r2 * 256);
        uint4 v3 = *(const uint4*)(Tb + (size_t)r3 * 256);
        uint4 v4 = *(const uint4*)(Tb + (size_t)r4 * 256);
        uint4 v5 = *(const uint4*)(Tb + (size_t)r5 * 256);
        uint4 v6 = *(const uint4*)(Tb + (size_t)r6 * 256);
        uint4 v7 = *(const uint4*)(Tb + (size_t)r7 * 256);
        ACC8(a, v0); ACC8(a, v1); ACC8(a, v2); ACC8(a, v3);
        ACC8(a, v4); ACC8(a, v5); ACC8(a, v6); ACC8(a, v7);
    }
    for (; i < end; ++i) {
        int r0 = x_idx[csr[i]];
        uint4 v0 = *(const uint4*)(Tb + (size_t)r0 * 256);
        ACC8(a, v0);
    }
    float inv = 1.f / (float)max(end - beg, 1);
    uint4 o;
    o.x = (unsigned)f2bf(a[0] * inv) | ((unsigned)f2bf(a[1] * inv) << 16);
    o.y = (unsigned)f2bf(a[2] * inv) | ((unsigned)f2bf(a[3] * inv) << 16);
    o.z = (unsigned)f2bf(a[4] * inv) | ((unsigned)f2bf(a[5] * inv) << 16);
    o.w = (unsigned)f2bf(a[6] * inv) | ((unsigned)f2bf(a[7] * inv) << 16);
    *(uint4*)((char*)AGG + (size_t)n * 256 + f * 16) = o;
}

// ---------------- layer-2 aggregation: dense gather, 8-deep unroll ----------------
__global__ __launch_bounds__(256) void agg_kernel(const unsigned short* __restrict__ X,
                                                  const int* __restrict__ rowptr,
                                                  const int* __restrict__ csr,
                                                  unsigned short* __restrict__ AGG) {
    const int t = threadIdx.x;
    const int lane = t & 63;
    const int f = lane & 15;
    const int n = blockIdx.x * 16 + (t >> 6) * 4 + (lane >> 4);
    int beg = rowptr[n], end = rowptr[n + 1];
    const char* Xb = (const char*)X + f * 16;
    float a[8];
#pragma unroll
    for (int k = 0; k < 8; ++k) a[k] = 0.f;
    int i = beg;
    for (; i + 8 <= end; i += 8) {            // 8 row-loads in flight
        int s0 = csr[i + 0], s1 = csr[i + 1], s2 = csr[i + 2], s3 = csr[i + 3];
        int s4 = csr[i + 4], s5 = csr[i + 5], s6 = csr[i + 6], s7 = csr[i + 7];
        uint4 v0 = *(const uint4*)(Xb + (size_t)s0 * 256);
        uint4 v1 = *(const uint4*)(Xb + (size_t)s1 * 256);
        uint4 v2 = *(const uint4*)(Xb + (size_t)s2 * 256);
        uint4 v3 = *(const uint4*)(Xb + (size_t)s3 * 256);
        uint4 v4 = *(const uint4*)(Xb + (size_t)s4 * 256);
        uint4 v5 = *(const uint4*)(Xb + (size_t)s5 * 256);
        uint4 v6 = *(const uint4*)(Xb + (size_t)s6 * 256);
        uint4 v7 = *(const uint4*)(Xb + (size_t)s7 * 256);
        ACC8(a, v0); ACC8(a, v1); ACC8(a, v2); ACC8(a, v3);
        ACC8(a, v4); ACC8(a, v5); ACC8(a, v6); ACC8(a, v7);
    }
    for (; i + 2 <= end; i += 2) {
        int s0 = csr[i], s1 = csr[i + 1];
        uint4 v0 = *(const uint4*)(Xb + (size_t)s0 * 256);
        uint4 v1 = *(const uint4*)(Xb + (size_t)s1 * 256);
        ACC8(a, v0); ACC8(a, v1);
    }
    if (i < end) {
        uint4 v0 = *(const uint4*)(Xb + (size_t)csr[i] * 256);
        ACC8(a, v0);
    }
    float inv = 1.f / (float)max(end - beg, 1);
    uint4 o;
    o.x = (unsigned)f2bf(a[0] * inv) | ((unsigned)f2bf(a[1] * inv) << 16);
    o.y = (unsigned)f2bf(a[2] * inv) | ((unsigned)f2bf(a[3] * inv) << 16);
    o.z = (unsigned)f2bf(a[4] * inv) | ((unsigned)f2bf(a[5] * inv) << 16);
    o.w = (unsigned)f2bf(a[6] * inv) | ((unsigned)f2bf(a[7] * inv) << 16);
    *(uint4*)((char*)AGG + (size_t)n * 256 + f * 16) = o;
}

// ---------------- fused SAGE linear via MFMA (layer 1: 2 tiles/block) ----------------
__global__ __launch_bounds__(256) void gemm_kernel(const unsigned short* __restrict__ A0,
                                                   const unsigned short* __restrict__ A1,
                                                   const unsigned short* __restrict__ wblob,
                                                   const float* __restrict__ bias,
                                                   unsigned short* __restrict__ Y) {
    __shared__ char lds[65536];
    const int t = threadIdx.x, lane = t & 63, w = t >> 6;

    {
        const char* src = (const char*)wblob + w * 16384 + lane * 16;
        char* dst = lds + w * 16384;
#pragma unroll
        for (int i = 0; i < 16; ++i) {
            __builtin_amdgcn_global_load_lds(
                (const __attribute__((address_space(1))) unsigned*)(src + i * 1024),
                (__attribute__((address_space(3))) unsigned*)(dst + i * 1024), 16, 0, 0);
        }
    }
    __syncthreads();

    const int kl = (lane >> 4) * 8;
    const int c     = lane & 15;
    const int rbase = (lane >> 4) * 4;

#pragma unroll 1
    for (int tt = 0; tt < 2; ++tt) {
        const int tile0 = blockIdx.x * 2 + tt;
        if (tile0 * 128 >= N_NODES) break;
        const int row0 = tile0 * 128 + w * 32;

        f32x4 acc[2][8];
#pragma unroll
        for (int rt = 0; rt < 2; ++rt)
#pragma unroll
            for (int tl = 0; tl < 8; ++tl) acc[rt][tl] = (f32x4){0.f, 0.f, 0.f, 0.f};

        int rA = min(row0 + (lane & 15),      N_NODES - 1);
        int rB = min(row0 + 16 + (lane & 15), N_NODES - 1);

#pragma unroll
        for (int km = 0; km < 8; ++km) {
            const unsigned short* A = (km < 4) ? A0 : A1;
            int k0 = (km & 3) * 32 + kl;
            bf16x8 a0 = *(const bf16x8*)(A + (size_t)rA * 128 + k0);
            bf16x8 a1 = *(const bf16x8*)(A + (size_t)rB * 128 + k0);
            const char* bbase = lds + km * 8192 + lane * 16;
#pragma unroll
            for (int tile = 0; tile < 8; ++tile) {
                bf16x8 b = *(const bf16x8*)(bbase + tile * 1024);
                acc[0][tile] = __builtin_amdgcn_mfma_f32_16x16x32_bf16(a0, b, acc[0][tile], 0, 0, 0);
                acc[1][tile] = __builtin_amdgcn_mfma_f32_16x16x32_bf16(a1, b, acc[1][tile], 0, 0, 0);
            }
        }

#pragma unroll
        for (int rt = 0; rt < 2; ++rt) {
#pragma unroll
            for (int tile = 0; tile < 8; ++tile) {
                int col = tile * 16 + c;
                float bv = bias[col];
#pragma unroll
                for (int j = 0; j < 4; ++j) {
                    int r = row0 + rt * 16 + rbase + j;
                    if (r < N_NODES)
                        Y[(size_t)r * 128 + col] = f2bf(fmaxf(acc[rt][tile][j] + bv, 0.f));
                }
            }
        }
    }
}

// ---------------- layer-2 GEMM with fused mean-pool (no y2 write) ----------------
__global__ __launch_bounds__(256) void gemm_pool_kernel(const unsigned short* __restrict__ A0,
                                                        const unsigned short* __restrict__ A1,
                                                        const unsigned short* __restrict__ wblob,
                                                        const float* __restrict__ bias,
                                                        const int* __restrict__ batch,
                                                        float* __restrict__ gsum) {
    __shared__ char lds[65536];
    const int t = threadIdx.x, lane = t & 63, w = t >> 6;
    const int brow0 = blockIdx.x * 128;
    const int row0  = brow0 + w * 32;

    {
        const char* src = (const char*)wblob + w * 16384 + lane * 16;
        char* dst = lds + w * 16384;
#pragma unroll
        for (int i = 0; i < 16; ++i) {
            __builtin_amdgcn_global_load_lds(
                (const __attribute__((address_space(1))) unsigned*)(src + i * 1024),
                (__attribute__((address_space(3))) unsigned*)(dst + i * 1024), 16, 0, 0);
        }
    }
    __syncthreads();

    f32x4 acc[2][8];
#pragma unroll
    for (int rt = 0; rt < 2; ++rt)
#pragma unroll
        for (int tl = 0; tl < 8; ++tl) acc[rt][tl] = (f32x4){0.f, 0.f, 0.f, 0.f};

    int rA = min(row0 + (lane & 15),      N_NODES - 1);
    int rB = min(row0 + 16 + (lane & 15), N_NODES - 1);
    const int kl = (lane >> 4) * 8;

#pragma unroll
    for (int km = 0; km < 8; ++km) {
        const unsigned short* A = (km < 4) ? A0 : A1;
        int k0 = (km & 3) * 32 + kl;
        bf16x8 a0 = *(const bf16x8*)(A + (size_t)rA * 128 + k0);
        bf16x8 a1 = *(const bf16x8*)(A + (size_t)rB * 128 + k0);
        const char* bbase = lds + km * 8192 + lane * 16;
#pragma unroll
        for (int tile = 0; tile < 8; ++tile) {
            bf16x8 b = *(const bf16x8*)(bbase + tile * 1024);
            acc[0][tile] = __builtin_amdgcn_mfma_f32_16x16x32_bf16(a0, b, acc[0][tile], 0, 0, 0);
            acc[1][tile] = __builtin_amdgcn_mfma_f32_16x16x32_bf16(a1, b, acc[1][tile], 0, 0, 0);
        }
    }

    // epilogue: relu(acc+bias) -> reuse weight LDS as 128x128 f32 tile
    __syncthreads();                       // all waves done reading weights
    float* ftile = (float*)lds;
    const int c     = lane & 15;
    const int rbase = (lane >> 4) * 4;
#pragma unroll
    for (int rt = 0; rt < 2; ++rt) {
#pragma unroll
        for (int tile = 0; tile < 8; ++tile) {
            int col = tile * 16 + c;
            float bv = bias[col];
#pragma unroll
            for (int j = 0; j < 4; ++j) {
                int lr = w * 32 + rt * 16 + rbase + j;
                ftile[lr * 128 + col] = fmaxf(acc[rt][tile][j] + bv, 0.f);
            }
        }
    }
    __syncthreads();

    // per-graph column partial sums (batch sorted): thread = (col, row-half)
    const int col  = t & 127;
    const int half = t >> 7;
    float s = 0.f;
    int curg = -1;
    for (int rr = 0; rr < 64; ++rr) {
        int r = brow0 + half * 64 + rr;
        if (r >= N_NODES) break;
        int g = batch[r];
        if (g != curg) {
            if (curg >= 0) atomicAdd(&gsum[curg * 128 + col], s);
            curg = g; s = 0.f;
        }
        s += ftile[(half * 64 + rr) * 128 + col];
    }
    if (curg >= 0) atomicAdd(&gsum[curg * 128 + col], s);
}

// ---------------- classifier ----------------
__global__ void final_kernel(const float* __restrict__ gsum, const int* __restrict__ batch,
                             const float* __restrict__ linW, const float* __restrict__ linb,
                             float* __restrict__ out) {
    int t = blockIdx.x * 256 + threadIdx.x;
    if (t >= N_GRAPHS * 10) return;
    int g = t / 10, j = t % 10;
    int bnd[2];
    for (int c = 0; c < 2; ++c) {
        int target = g + c;
        int lo = 0, hi = N_NODES;
        while (lo < hi) { int mid = (lo + hi) >> 1; if (batch[mid] < target) lo = mid + 1; else hi = mid; }
        bnd[c] = lo;
    }
    float invc = 1.f / (float)max(bnd[1] - bnd[0], 1);
    float s = 0.f;
    for (int k = 0; k < 128; ++k) s += gsum[g * 128 + k] * linW[j * 128 + k];
    out[t] = linb[j] + s * invc;
}

extern "C" void kernel_launch(void* const* d_in, const int* in_sizes, int n_in,
                              void* d_out, int out_size, void* d_ws, size_t ws_size,
                              hipStream_t stream) {
    const int*   x_idx = (const int*)d_in[0];
    const int*   eidx  = (const int*)d_in[1];   // [2][N_EDGES]
    const int*   batch = (const int*)d_in[2];
    const float* table = (const float*)d_in[3];
    const float* Wl1   = (const float*)d_in[4];
    const float* bl1   = (const float*)d_in[5];
    const float* Wr1   = (const float*)d_in[6];
    const float* Wl2   = (const float*)d_in[7];
    const float* bl2   = (const float*)d_in[8];
    const float* Wr2   = (const float*)d_in[9];
    const float* linW  = (const float*)d_in[10];
    const float* linb  = (const float*)d_in[11];
    float*       out   = (float*)d_out;

    const int* src = eidx;
    const int* dst = eidx + N_EDGES;

    // workspace layout (~56 MB); feature buffers row-major [N][128] bf16
    unsigned short* X    = (unsigned short*)d_ws;                 // x0
    unsigned short* AGG  = X   + (size_t)N_NODES * 128;           // agg
    unsigned short* Y1   = AGG + (size_t)N_NODES * 128;           // y1
    unsigned short* blob = Y1  + (size_t)N_NODES * 128;           // 2 x 64KB frag-ordered
    unsigned short* TBL  = blob + 65536;                          // bf16 table [1000][128]
    float* gsum = (float*)(TBL + VOCAB * 128);
    int* cnt    = (int*)(gsum + N_GRAPHS * 128);
    int* rowptr = cnt + N_NODES;                                  // N_NODES+1
    int* csr    = rowptr + (N_NODES + 1);                         // N_EDGES
    int* bsum   = csr + N_EDGES;                                  // SCAN_BLOCKS
    int* part   = bsum + SCAN_BLOCKS;                             // NCHUNK x N_NODES
    int* off    = part + (size_t)NCHUNK * N_NODES;                // NCHUNK x N_NODES

    // k1: histogram | embed | table-cvt | weight prep + gsum zero (one launch)
    k1_kernel<<<K1_HIST + K1_EMBED + K1_TBL + K1_PREP, 256, 0, stream>>>(
        dst, part, x_idx, table, X, TBL, Wl1, Wr1, Wl2, Wr2, blob, gsum);
    cntsum_kernel   <<<SCAN_BLOCKS, 256, 0, stream>>>(part, cnt, bsum);
    rowptroff_kernel<<<SCAN_BLOCKS, 256, 0, stream>>>(cnt, bsum, part, rowptr, off);
    scatter_kernel  <<<NCHUNK * NRANGE, 256, 0, stream>>>(src, dst, off, csr);

    // layer 1: gather through L2-resident bf16 table
    agg1_kernel<<<dim3(N_NODES / 16), 256, 0, stream>>>(TBL, x_idx, rowptr, csr, AGG);
    gemm_kernel<<<dim3((N_NODES + 255) / 256), 256, 0, stream>>>(AGG, X, blob, bl1, Y1);
    // layer 2 (+ fused mean pool)
    agg_kernel      <<<dim3(N_NODES / 16), 256, 0, stream>>>(Y1, rowptr, csr, AGG);
    gemm_pool_kernel<<<dim3((N_NODES + 127) / 128), 256, 0, stream>>>(AGG, Y1, blob + 32768, bl2, batch, gsum);

    final_kernel<<<3, 256, 0, stream>>>(gsum, batch, linW, linb, out);
}